// Round 4
// baseline (264.570 us; speedup 1.0000x reference)
//
#include <hip/hip_runtime.h>
#include <math.h>

#define CIN_    512
#define COUT_   512
#define LATENT_ 512
#define NB_     8
#define HH_     64
#define WW_     64

typedef float f32x16 __attribute__((ext_vector_type(16)));
typedef short bf16x8v __attribute__((ext_vector_type(8)));

__device__ inline unsigned short f2bf(float f) {
    union { float f; unsigned u; } v; v.f = f;
    unsigned r = v.u + 0x7fffu + ((v.u >> 16) & 1u);
    return (unsigned short)(r >> 16);
}

// Async global->LDS 16B copy. LDS dest must be wave-uniform base; HW adds lane*16.
__device__ __forceinline__ void gl_lds16(const void* g, void* l) {
    __builtin_amdgcn_global_load_lds(
        (const __attribute__((address_space(1))) unsigned int*)g,
        (__attribute__((address_space(3))) unsigned int*)l,
        16, 0, 0);
}

// ============ K1: fused wsq (blocks 0..1023) + wprep (1024..1311) + style (1312..1375)
// R4: wprep now emits wb in FRAGMENT-LINEAR layout:
//   wb[(tap*32+cb)*1024 + g*64 + l] (16B chunks), chunk = data for
//   co = g*32 + (l&31), ci(local) = (l>>5)*8 .. +7.
// So conv's B-frag ds_read_b128 is base + lane*16B -> zero bank conflicts.
__global__ __launch_bounds__(256) void prep1(
    const float* __restrict__ w, const float* __restrict__ dlat,
    const float* __restrict__ mw, const float* __restrict__ mb,
    float* __restrict__ wsq, unsigned short* __restrict__ wb,
    float* __restrict__ s)
{
    __shared__ float smem[16 * 521];   // wprep transpose buffer; style reuses [0..767]
    const float RC_W = 0.0147313912747197f;   // 1/sqrt(9*512)
    const float RC_S = 0.0441941738241592f;   // 1/sqrt(512)
    int b = blockIdx.x;
    int t = threadIdx.x;

    if (b < 1024) {
        // ---- wsq[ci][co] = sum_tap w^2 (fp32, exact demod) ----
        int idx = b * 256 + t;
        float acc = 0.f;
#pragma unroll
        for (int tap = 0; tap < 9; ++tap) {
            float v = w[tap * (CIN_ * COUT_) + idx];
            acc += v * v;
        }
        wsq[idx] = acc;
    } else if (b < 1312) {
        // ---- wprep: fragment-linear wb (see header comment) ----
        int bb  = b - 1024;
        int tap = bb / 32;
        int cb  = bb % 32;
        for (int idx = t; idx < 16 * 512; idx += 256) {
            int ci = idx >> 9;
            int co = idx & 511;
            smem[ci * 521 + co] = w[((size_t)tap * 512 + cb * 16 + ci) * 512 + co];
        }
        __syncthreads();
        unsigned short* dst = wb + (size_t)(tap * 32 + cb) * 1024 * 8;  // 8192 u16
        // 8192 u16 = 2048 ushort4; p -> chunk = p>>1, e0 = (p&1)*4
        for (int p = t; p < 2048; p += 256) {
            int l  = (p >> 1) & 63;
            int g  = p >> 7;
            int co = g * 32 + (l & 31);
            int ci = (l >> 5) * 8 + (p & 1) * 4;
            ushort4 o4;
            o4.x = f2bf(smem[(ci + 0) * 521 + co] * RC_W);
            o4.y = f2bf(smem[(ci + 1) * 521 + co] * RC_W);
            o4.z = f2bf(smem[(ci + 2) * 521 + co] * RC_W);
            o4.w = f2bf(smem[(ci + 3) * 521 + co] * RC_W);
            *(ushort4*)&dst[p * 4] = o4;
        }
    } else {
        // ---- style: s[n][ci] = dlat . (mw*RC_S) + mb + 1 ----
        int bb  = b - 1312;
        int n   = bb >> 3;
        int ci0 = (bb & 7) * 64;
        for (int i = t; i < LATENT_; i += 256) smem[i] = dlat[n * LATENT_ + i];
        __syncthreads();
        int cil  = t & 63;
        int part = t >> 6;
        const float* mwp = mw + ci0 + cil;
        float a0 = 0.f, a1 = 0.f;
        int l0 = part * 128;
#pragma unroll 4
        for (int l = l0; l < l0 + 128; l += 2) {
            a0 += smem[l]     * mwp[(size_t)l * CIN_];
            a1 += smem[l + 1] * mwp[(size_t)(l + 1) * CIN_];
        }
        smem[512 + part * 64 + cil] = a0 + a1;
        __syncthreads();
        if (t < 64) {
            float r = smem[512 + t] + smem[576 + t] + smem[640 + t] + smem[704 + t];
            s[n * CIN_ + ci0 + t] = r * RC_S + mb[ci0 + t] + 1.0f;
        }
    }
}

// ============ K2: fused demod (blocks 0..63) + xprep (64..1599)
// R4: xprep restructured to 1536 blocks (n x cb x 6 row-groups), each looping
// 11 hp rows — amortizes block setup / s-load, keeps coalescing.
__global__ __launch_bounds__(256) void prep2(
    const float* __restrict__ x, const float* __restrict__ s,
    const float* __restrict__ wsq, float* __restrict__ dmod,
    unsigned short* __restrict__ xt)
{
    __shared__ float smem[16 * 67 + 16];   // 1088 floats; demod uses [0..767]
    int b = blockIdx.x;
    int t = threadIdx.x;

    if (b < 64) {
        // ---- demod: d[n][co] = rsqrt(RC_W^2 * sum_ci s^2 * wsq + 1e-8) ----
        const float RCW2 = 1.0f / 4608.0f;
        int n   = b >> 3;
        int co0 = (b & 7) * 64;
        for (int i = t; i < CIN_; i += 256) { float v = s[n * CIN_ + i]; smem[i] = v * v; }
        __syncthreads();
        int col  = t & 63;
        int part = t >> 6;
        const float* wp = wsq + co0 + col;
        float a0 = 0.f, a1 = 0.f;
        int c0 = part * 128;
#pragma unroll 4
        for (int ci = c0; ci < c0 + 128; ci += 2) {
            a0 += smem[ci]     * wp[(size_t)ci * COUT_];
            a1 += smem[ci + 1] * wp[(size_t)(ci + 1) * COUT_];
        }
        smem[512 + part * 64 + col] = a0 + a1;
        __syncthreads();
        if (t < 64) {
            float r = smem[512 + t] + smem[576 + t] + smem[640 + t] + smem[704 + t];
            dmod[n * COUT_ + co0 + t] = rsqrtf(RCW2 * r + 1e-8f);
        }
    } else {
        int bb = b - 64;                 // n(8) x cb(32) x rg(6)
        int rg = bb % 6;
        int cb = (bb / 6) % 32;
        int n  = bb / (6 * 32);

        if (t < 16) smem[16 * 67 + t] = s[n * CIN_ + cb * 16 + t];

        for (int hp = rg * 11; hp < rg * 11 + 11; ++hp) {
            int gh = hp - 1;
            bool rowok = (gh >= 0) && (gh < HH_);
            if (rowok) {
                const float* src = &x[(((size_t)n * CIN_ + cb * 16) * HH_ + gh) * WW_];
                int ci = t >> 4;
                int g0 = (t & 15) * 4;
                float4 v = *(const float4*)&src[(size_t)ci * (HH_ * WW_) + g0];
                float* dstl = &smem[ci * 67 + g0];
                dstl[0] = v.x; dstl[1] = v.y; dstl[2] = v.z; dstl[3] = v.w;
            }
            __syncthreads();

            unsigned short* dst = xt + (((size_t)(n * 32 + cb) * 66 + hp) * 66) * 16;
            for (int p = t; p < 264; p += 256) {
                int e   = p * 4;
                int wp_ = e >> 4;
                int cie = e & 15;       // 0,4,8,12
                int gw  = wp_ - 1;
                float vv0 = 0.f, vv1 = 0.f, vv2 = 0.f, vv3 = 0.f;
                if (rowok && gw >= 0 && gw < WW_) {
                    vv0 = smem[(cie + 0) * 67 + gw] * smem[16 * 67 + cie + 0];
                    vv1 = smem[(cie + 1) * 67 + gw] * smem[16 * 67 + cie + 1];
                    vv2 = smem[(cie + 2) * 67 + gw] * smem[16 * 67 + cie + 2];
                    vv3 = smem[(cie + 3) * 67 + gw] * smem[16 * 67 + cie + 3];
                }
                ushort4 o4;
                o4.x = f2bf(vv0); o4.y = f2bf(vv1); o4.z = f2bf(vv2); o4.w = f2bf(vv3);
                *(ushort4*)&dst[e] = o4;
            }
            __syncthreads();
        }
    }
}

// ============ main conv: implicit GEMM on 32x32x16 bf16 MFMA
// R4: (1) ws staged in fragment-linear layout -> B-frag reads are base+lane*16B,
//     zero bank conflicts. (2) xs XOR-swizzle chunk^=(chunk>>3)&7 applied on
//     global-source side (gl_lds writes linear) + on read address -> A-frag
//     conflicts drop to <=2-way (free).
__global__ __launch_bounds__(256, 2) void conv_mfma(
    const unsigned short* __restrict__ xt,
    const unsigned short* __restrict__ wb,
    const float* __restrict__ dmod,
    float* __restrict__ out)
{
    __shared__ __align__(16) union {
        struct { unsigned short xs[2880]; unsigned short ws[36864]; } s;  // 79488 B
        float o[64 * 129];                                                // 33024 B
    } sm;

    int b   = blockIdx.x;
    int cot = b & 1;              // 2 co tiles of 256
    int wt_ = (b >> 1) & 3;
    int ht  = (b >> 3) & 7;
    int n   = b >> 6;
    int h0 = ht * 8, w0 = wt_ * 16, co0 = cot * 256;

    int t    = threadIdx.x;
    int wv   = t >> 6, lane = t & 63;
    int mh   = wv >> 1, nh = wv & 1;     // 2M x 2N wave grid
    int l5   = lane & 31, half = lane >> 5;

    f32x16 acc[2][4];
#pragma unroll
    for (int ms = 0; ms < 2; ++ms)
#pragma unroll
        for (int ns = 0; ns < 4; ++ns)
#pragma unroll
            for (int i = 0; i < 16; ++i) acc[ms][ns][i] = 0.f;

    for (int cb = 0; cb < 32; ++cb) {
        // stage x halo tile: 360 16B chunks, xs swizzled: LDS chunk li holds
        // logical chunk sig(li), sig(c) = c ^ ((c>>3)&7) (involution).
        const unsigned short* xb = xt + (((size_t)(n * 32 + cb) * 66 + h0) * 66 + w0) * 16;
        {
            int li = t;
            int m  = li ^ ((li >> 3) & 7);
            gl_lds16(&xb[(m / 36) * 1056 + (m % 36) * 8], &sm.s.xs[(li & ~63) * 8]);
            li = t + 256;
            if (li < 360) {
                m = li ^ ((li >> 3) & 7);
                gl_lds16(&xb[(m / 36) * 1056 + (m % 36) * 8], &sm.s.xs[(li & ~63) * 8]);
            }
        }
        // stage weights: fragment-linear, 512 chunks of 16B per tap (this co half).
        const unsigned short* wbb = wb + ((size_t)cb * 1024 + cot * 512) * 8;
#pragma unroll
        for (int tap = 0; tap < 9; ++tap) {
            const unsigned short* tsrc = wbb + (size_t)tap * 32 * 1024 * 8;
            gl_lds16(&tsrc[t * 8],         &sm.s.ws[tap * 4096 + (t & ~63) * 8]);
            gl_lds16(&tsrc[(t + 256) * 8], &sm.s.ws[tap * 4096 + ((t + 256) & ~63) * 8]);
        }
        __syncthreads();   // vmcnt(0) drain + barrier

#pragma unroll
        for (int tap = 0; tap < 9; ++tap) {
            int kh = tap / 3, kw = tap - 3 * (tap / 3);
            bf16x8v bfr[4], afr[2];
#pragma unroll
            for (int ns = 0; ns < 4; ++ns) {
                // fragment-linear: frag (nh,ns) at chunk (nh*4+ns)*64 + lane
                bfr[ns] = *(const bf16x8v*)&sm.s.ws[tap * 4096 + ((nh * 4 + ns) * 64 + lane) * 8];
            }
#pragma unroll
            for (int ms = 0; ms < 2; ++ms) {
                int pr = mh * 4 + ms * 2 + (l5 >> 4);
                int pc = l5 & 15;
                int pos = (pr + kh) * 18 + (pc + kw);
                int ch  = pos * 2 + half;
                ch ^= (ch >> 3) & 7;           // xs swizzle (matches staging)
                afr[ms] = *(const bf16x8v*)&sm.s.xs[ch * 8];
            }
#pragma unroll
            for (int ms = 0; ms < 2; ++ms)
#pragma unroll
                for (int ns = 0; ns < 4; ++ns)
                    acc[ms][ns] = __builtin_amdgcn_mfma_f32_32x32x16_bf16(
                        afr[ms], bfr[ns], acc[ms][ns], 0, 0, 0);
        }
        __syncthreads();
    }

    // epilogue: demod + LDS transpose + coalesced float4 stores, 4 passes of 64 co.
    for (int p = 0; p < 4; ++p) {
        __syncthreads();
        if (nh == (p >> 1)) {
#pragma unroll
            for (int q = 0; q < 2; ++q) {
                int bco = q * 32 + l5;
                float dv = dmod[n * COUT_ + co0 + p * 64 + bco];
#pragma unroll
                for (int ms = 0; ms < 2; ++ms) {
#pragma unroll
                    for (int reg = 0; reg < 16; ++reg) {
                        int ml = (reg & 3) + 8 * (reg >> 2) + 4 * half;
                        int m  = mh * 64 + ms * 32 + ml;      // 0..127 spatial
                        sm.o[bco * 129 + m] = acc[ms][(p & 1) * 2 + q][reg] * dv;
                    }
                }
            }
        }
        __syncthreads();
        for (int j = t; j < 2048; j += 256) {
            int wq = j & 3;
            int pairidx = j >> 2;
            int row  = pairidx & 7;
            int bco2 = pairidx >> 3;          // 0..63
            int co = co0 + p * 64 + bco2;
            const float* src = &sm.o[bco2 * 129 + row * 16 + wq * 4];
            float4 v = make_float4(src[0], src[1], src[2], src[3]);
            *(float4*)&out[(((size_t)n * COUT_ + co) * HH_ + h0 + row) * WW_ + w0 + wq * 4] = v;
        }
    }
}

extern "C" void kernel_launch(void* const* d_in, const int* in_sizes, int n_in,
                              void* d_out, int out_size, void* d_ws, size_t ws_size,
                              hipStream_t stream) {
    const float* x    = (const float*)d_in[0];
    const float* dlat = (const float*)d_in[1];
    const float* w    = (const float*)d_in[2];
    const float* mw   = (const float*)d_in[3];
    const float* mb   = (const float*)d_in[4];
    float* out = (float*)d_out;

    char* ws = (char*)d_ws;
    float* s    = (float*)(ws);                       // 4096 f
    float* dmod = (float*)(ws + 16384);               // 4096 f
    float* wsq  = (float*)(ws + 32768);               // 262144 f
    unsigned short* xt = (unsigned short*)(ws + 1081344);    // 17,842,176 u16
    unsigned short* wb = (unsigned short*)(ws + 36765696);   // 2,359,296 u16

    prep1<<<1376, 256, 0, stream>>>(w, dlat, mw, mb, wsq, wb, s);
    prep2<<<64 + NB_ * 32 * 6, 256, 0, stream>>>(x, s, wsq, dmod, xt);
    conv_mfma<<<512, 256, 0, stream>>>(xt, wb, dmod, out);
}

// Round 6
// 257.364 us; speedup vs baseline: 1.0280x; 1.0280x over previous
//
#include <hip/hip_runtime.h>
#include <math.h>

#define CIN_    512
#define COUT_   512
#define LATENT_ 512
#define NB_     8
#define HH_     64
#define WW_     64

typedef float f32x16 __attribute__((ext_vector_type(16)));
typedef short bf16x8v __attribute__((ext_vector_type(8)));

__device__ inline unsigned short f2bf(float f) {
    union { float f; unsigned u; } v; v.f = f;
    unsigned r = v.u + 0x7fffu + ((v.u >> 16) & 1u);
    return (unsigned short)(r >> 16);
}

// Async global->LDS 16B copy. LDS dest must be wave-uniform base; HW adds lane*16.
__device__ __forceinline__ void gl_lds16(const void* g, void* l) {
    __builtin_amdgcn_global_load_lds(
        (const __attribute__((address_space(1))) unsigned int*)g,
        (__attribute__((address_space(3))) unsigned int*)l,
        16, 0, 0);
}

// ============ K1: fused wsq (blocks 0..1023) + wprep (1024..1311) + style (1312..1375)
// wprep emits wb in FRAGMENT-LINEAR layout:
//   wb[(tap*32+cb)*1024 + g*64 + l] (16B chunks), chunk = data for
//   co = g*32 + (l&31), ci(local) = (l>>5)*8 .. +7.
__global__ __launch_bounds__(256) void prep1(
    const float* __restrict__ w, const float* __restrict__ dlat,
    const float* __restrict__ mw, const float* __restrict__ mb,
    float* __restrict__ wsq, unsigned short* __restrict__ wb,
    float* __restrict__ s)
{
    __shared__ float smem[16 * 521];
    const float RC_W = 0.0147313912747197f;   // 1/sqrt(9*512)
    const float RC_S = 0.0441941738241592f;   // 1/sqrt(512)
    int b = blockIdx.x;
    int t = threadIdx.x;

    if (b < 1024) {
        int idx = b * 256 + t;
        float acc = 0.f;
#pragma unroll
        for (int tap = 0; tap < 9; ++tap) {
            float v = w[tap * (CIN_ * COUT_) + idx];
            acc += v * v;
        }
        wsq[idx] = acc;
    } else if (b < 1312) {
        int bb  = b - 1024;
        int tap = bb / 32;
        int cb  = bb % 32;
        for (int idx = t; idx < 16 * 512; idx += 256) {
            int ci = idx >> 9;
            int co = idx & 511;
            smem[ci * 521 + co] = w[((size_t)tap * 512 + cb * 16 + ci) * 512 + co];
        }
        __syncthreads();
        unsigned short* dst = wb + (size_t)(tap * 32 + cb) * 1024 * 8;
        for (int p = t; p < 2048; p += 256) {
            int l  = (p >> 1) & 63;
            int g  = p >> 7;
            int co = g * 32 + (l & 31);
            int ci = (l >> 5) * 8 + (p & 1) * 4;
            ushort4 o4;
            o4.x = f2bf(smem[(ci + 0) * 521 + co] * RC_W);
            o4.y = f2bf(smem[(ci + 1) * 521 + co] * RC_W);
            o4.z = f2bf(smem[(ci + 2) * 521 + co] * RC_W);
            o4.w = f2bf(smem[(ci + 3) * 521 + co] * RC_W);
            *(ushort4*)&dst[p * 4] = o4;
        }
    } else {
        int bb  = b - 1312;
        int n   = bb >> 3;
        int ci0 = (bb & 7) * 64;
        for (int i = t; i < LATENT_; i += 256) smem[i] = dlat[n * LATENT_ + i];
        __syncthreads();
        int cil  = t & 63;
        int part = t >> 6;
        const float* mwp = mw + ci0 + cil;
        float a0 = 0.f, a1 = 0.f;
        int l0 = part * 128;
#pragma unroll 4
        for (int l = l0; l < l0 + 128; l += 2) {
            a0 += smem[l]     * mwp[(size_t)l * CIN_];
            a1 += smem[l + 1] * mwp[(size_t)(l + 1) * CIN_];
        }
        smem[512 + part * 64 + cil] = a0 + a1;
        __syncthreads();
        if (t < 64) {
            float r = smem[512 + t] + smem[576 + t] + smem[640 + t] + smem[704 + t];
            s[n * CIN_ + ci0 + t] = r * RC_S + mb[ci0 + t] + 1.0f;
        }
    }
}

// ============ K2: fused demod (blocks 0..63) + xprep (64..1599)
__global__ __launch_bounds__(256) void prep2(
    const float* __restrict__ x, const float* __restrict__ s,
    const float* __restrict__ wsq, float* __restrict__ dmod,
    unsigned short* __restrict__ xt)
{
    __shared__ float smem[16 * 67 + 16];
    int b = blockIdx.x;
    int t = threadIdx.x;

    if (b < 64) {
        const float RCW2 = 1.0f / 4608.0f;
        int n   = b >> 3;
        int co0 = (b & 7) * 64;
        for (int i = t; i < CIN_; i += 256) { float v = s[n * CIN_ + i]; smem[i] = v * v; }
        __syncthreads();
        int col  = t & 63;
        int part = t >> 6;
        const float* wp = wsq + co0 + col;
        float a0 = 0.f, a1 = 0.f;
        int c0 = part * 128;
#pragma unroll 4
        for (int ci = c0; ci < c0 + 128; ci += 2) {
            a0 += smem[ci]     * wp[(size_t)ci * COUT_];
            a1 += smem[ci + 1] * wp[(size_t)(ci + 1) * COUT_];
        }
        smem[512 + part * 64 + col] = a0 + a1;
        __syncthreads();
        if (t < 64) {
            float r = smem[512 + t] + smem[576 + t] + smem[640 + t] + smem[704 + t];
            dmod[n * COUT_ + co0 + t] = rsqrtf(RCW2 * r + 1e-8f);
        }
    } else {
        int bb = b - 64;                 // n(8) x cb(32) x rg(6)
        int rg = bb % 6;
        int cb = (bb / 6) % 32;
        int n  = bb / (6 * 32);

        if (t < 16) smem[16 * 67 + t] = s[n * CIN_ + cb * 16 + t];

        for (int hp = rg * 11; hp < rg * 11 + 11; ++hp) {
            int gh = hp - 1;
            bool rowok = (gh >= 0) && (gh < HH_);
            if (rowok) {
                const float* src = &x[(((size_t)n * CIN_ + cb * 16) * HH_ + gh) * WW_];
                int ci = t >> 4;
                int g0 = (t & 15) * 4;
                float4 v = *(const float4*)&src[(size_t)ci * (HH_ * WW_) + g0];
                float* dstl = &smem[ci * 67 + g0];
                dstl[0] = v.x; dstl[1] = v.y; dstl[2] = v.z; dstl[3] = v.w;
            }
            __syncthreads();

            unsigned short* dst = xt + (((size_t)(n * 32 + cb) * 66 + hp) * 66) * 16;
            for (int p = t; p < 264; p += 256) {
                int e   = p * 4;
                int wp_ = e >> 4;
                int cie = e & 15;
                int gw  = wp_ - 1;
                float vv0 = 0.f, vv1 = 0.f, vv2 = 0.f, vv3 = 0.f;
                if (rowok && gw >= 0 && gw < WW_) {
                    vv0 = smem[(cie + 0) * 67 + gw] * smem[16 * 67 + cie + 0];
                    vv1 = smem[(cie + 1) * 67 + gw] * smem[16 * 67 + cie + 1];
                    vv2 = smem[(cie + 2) * 67 + gw] * smem[16 * 67 + cie + 2];
                    vv3 = smem[(cie + 3) * 67 + gw] * smem[16 * 67 + cie + 3];
                }
                ushort4 o4;
                o4.x = f2bf(vv0); o4.y = f2bf(vv1); o4.z = f2bf(vv2); o4.w = f2bf(vv3);
                *(ushort4*)&dst[e] = o4;
            }
            __syncthreads();
        }
    }
}

// ============ main conv: implicit GEMM on 32x32x16 bf16 MFMA
// R6: R5's tap-pipelined schedule (T3+T4+T5) with the LDS-overflow bug fixed:
// xs padded 384 -> 512 chunks per buffer so the uniform 2-op stage_xs
// (chunks 0..511) stays inside the buffer. R5 wrote chunks 384..511 of xs[1]
// over ws[0] -> garbage weights (absmax 129).
// Schedule: 288 steps (32 cb x 9 taps); ws = 3-deep ring (8KB/tap), stage k+2
// into ws[(tap+2)%3]; xs double-buffered by cb parity, prefetched at tap==4.
// Counted vmcnt(2)/(4) -- never 0 -- + one raw s_barrier per step.
__global__ __launch_bounds__(256, 2) void conv_mfma(
    const unsigned short* __restrict__ xt,
    const unsigned short* __restrict__ wb,
    const float* __restrict__ dmod,
    float* __restrict__ out)
{
    __shared__ __align__(16) union {
        struct {
            unsigned short xs[2][512 * 8];   // 2 x 8192 B (chunks 360.. are pad)
            unsigned short ws[3][4096];      // 3 x 8192 B
        } s;                                  // 40960 B
        float o[64 * 129];                    // 33024 B
    } sm;

    int b   = blockIdx.x;
    int cot = b & 1;              // 2 co tiles of 256
    int wt_ = (b >> 1) & 3;
    int ht  = (b >> 3) & 7;
    int n   = b >> 6;
    int h0 = ht * 8, w0 = wt_ * 16, co0 = cot * 256;

    int t    = threadIdx.x;
    int wv   = t >> 6, lane = t & 63;
    int mh   = wv >> 1, nh = wv & 1;     // 2M x 2N wave grid
    int l5   = lane & 31, half = lane >> 5;

    // Precomputed per-thread staging offsets (constant across steps).
    // ws: chunks t and t+256 of 512; LDS dest wave-uniform (t&~63)*16B.
    const int wsrc0 = t * 8, wsrc1 = (t + 256) * 8;
    const int wdst0 = (t & ~63) * 8, wdst1 = ((t + 256) & ~63) * 8;
    // xs: 512 chunks staged (360 real + pad), swizzle sig(c)=c^((c>>3)&7) on
    // SOURCE, linear LDS dest. Pad chunks clamp to a harmless source chunk.
    int m0 = t ^ ((t >> 3) & 7);
    int li1 = t + 256;
    int m1 = li1 ^ ((li1 >> 3) & 7); if (m1 > 359) m1 = 359;
    const int xsrc0 = (m0 / 36) * 1056 + (m0 % 36) * 8;
    const int xsrc1 = (m1 / 36) * 1056 + (m1 % 36) * 8;
    const int xdst0 = (t & ~63) * 8, xdst1 = ((t + 256) & ~63) * 8;

    f32x16 acc[2][4];
#pragma unroll
    for (int ms = 0; ms < 2; ++ms)
#pragma unroll
        for (int ns = 0; ns < 4; ++ns)
#pragma unroll
            for (int i = 0; i < 16; ++i) acc[ms][ns][i] = 0.f;

    // ---- staging helpers ----
    auto stage_ws = [&](int cb2, int tap2, int q) {
        const unsigned short* tsrc = wb + ((size_t)(tap2 * 32 + cb2) * 1024 + cot * 512) * 8;
        unsigned short* d = (unsigned short*)sm.s.ws[q];
        gl_lds16(&tsrc[wsrc0], &d[wdst0]);
        gl_lds16(&tsrc[wsrc1], &d[wdst1]);
    };
    auto stage_xs = [&](int cb2, int bq) {
        const unsigned short* xb2 = xt + (((size_t)(n * 32 + cb2) * 66 + h0) * 66 + w0) * 16;
        unsigned short* d = (unsigned short*)sm.s.xs[bq];
        gl_lds16(&xb2[xsrc0], &d[xdst0]);
        gl_lds16(&xb2[xsrc1], &d[xdst1]);
    };

    // ---- prologue: stage steps 0,1 + x tile for cb 0; full drain once ----
    stage_ws(0, 0, 0);
    stage_ws(0, 1, 1);
    stage_xs(0, 0);
    asm volatile("s_waitcnt vmcnt(0)" ::: "memory");
    __builtin_amdgcn_s_barrier();

    for (int cb = 0; cb < 32; ++cb) {
        const unsigned short* xsb = (const unsigned short*)sm.s.xs[cb & 1];
#pragma unroll
        for (int tap = 0; tap < 9; ++tap) {
            const int p  = tap % 3;            // read buffer (k%3 == tap%3)
            const int q2 = (tap + 2) % 3;      // stage target buffer
            const int kh = tap / 3, kw = tap % 3;

            // [A] LDS -> register fragments (compiler inserts lgkmcnt before MFMA)
            bf16x8v bfr[4], afr[2];
            const unsigned short* wsb = (const unsigned short*)sm.s.ws[p];
#pragma unroll
            for (int ns = 0; ns < 4; ++ns)
                bfr[ns] = *(const bf16x8v*)&wsb[((nh * 4 + ns) * 64 + lane) * 8];
#pragma unroll
            for (int ms = 0; ms < 2; ++ms) {
                int pr = mh * 4 + ms * 2 + (l5 >> 4);
                int pc = l5 & 15;
                int pos = (pr + kh) * 18 + (pc + kw);
                int ch  = pos * 2 + half;
                ch ^= (ch >> 3) & 7;
                afr[ms] = *(const bf16x8v*)&xsb[ch * 8];
            }

            // [B] stage ws for step k+2 (clamped at tail; uniform issue count)
            {
                int tap2 = tap + 2, cb2 = cb;
                if (tap2 >= 9) { tap2 -= 9; cb2 = cb + 1; }
                if (cb2 > 31) cb2 = 31;
                stage_ws(cb2, tap2, q2);
            }
            // [C] prefetch next cb's x tile mid-cb
            if (tap == 4) {
                int cb2 = (cb + 1 > 31) ? 31 : cb + 1;
                stage_xs(cb2, (cb + 1) & 1);
            }

            // [D] MFMA cluster
            __builtin_amdgcn_s_setprio(1);
#pragma unroll
            for (int ms = 0; ms < 2; ++ms)
#pragma unroll
                for (int ns = 0; ns < 4; ++ns)
                    acc[ms][ns] = __builtin_amdgcn_mfma_f32_32x32x16_bf16(
                        afr[ms], bfr[ns], acc[ms][ns], 0, 0, 0);
            __builtin_amdgcn_s_setprio(0);

            // [E] counted wait (stage issued LAST step must be complete) + barrier
            if (tap == 4) asm volatile("s_waitcnt vmcnt(4)" ::: "memory");
            else          asm volatile("s_waitcnt vmcnt(2)" ::: "memory");
            __builtin_amdgcn_s_barrier();
        }
    }

    // explicit drain: tail stages must land before LDS union is reused as o
    asm volatile("s_waitcnt vmcnt(0)" ::: "memory");

    // epilogue: demod + LDS transpose + coalesced float4 stores, 4 passes of 64 co.
    for (int pss = 0; pss < 4; ++pss) {
        __syncthreads();
        if (nh == (pss >> 1)) {
#pragma unroll
            for (int q = 0; q < 2; ++q) {
                int bco = q * 32 + l5;
                float dv = dmod[n * COUT_ + co0 + pss * 64 + bco];
#pragma unroll
                for (int ms = 0; ms < 2; ++ms) {
#pragma unroll
                    for (int reg = 0; reg < 16; ++reg) {
                        int ml = (reg & 3) + 8 * (reg >> 2) + 4 * half;
                        int m  = mh * 64 + ms * 32 + ml;
                        sm.o[bco * 129 + m] = acc[ms][(pss & 1) * 2 + q][reg] * dv;
                    }
                }
            }
        }
        __syncthreads();
        for (int j = t; j < 2048; j += 256) {
            int wq = j & 3;
            int pairidx = j >> 2;
            int row  = pairidx & 7;
            int bco2 = pairidx >> 3;
            int co = co0 + pss * 64 + bco2;
            const float* src = &sm.o[bco2 * 129 + row * 16 + wq * 4];
            float4 v = make_float4(src[0], src[1], src[2], src[3]);
            *(float4*)&out[(((size_t)n * COUT_ + co) * HH_ + h0 + row) * WW_ + w0 + wq * 4] = v;
        }
    }
}

extern "C" void kernel_launch(void* const* d_in, const int* in_sizes, int n_in,
                              void* d_out, int out_size, void* d_ws, size_t ws_size,
                              hipStream_t stream) {
    const float* x    = (const float*)d_in[0];
    const float* dlat = (const float*)d_in[1];
    const float* w    = (const float*)d_in[2];
    const float* mw   = (const float*)d_in[3];
    const float* mb   = (const float*)d_in[4];
    float* out = (float*)d_out;

    char* ws = (char*)d_ws;
    float* s    = (float*)(ws);                       // 4096 f
    float* dmod = (float*)(ws + 16384);               // 4096 f
    float* wsq  = (float*)(ws + 32768);               // 262144 f
    unsigned short* xt = (unsigned short*)(ws + 1081344);    // 17,842,176 u16
    unsigned short* wb = (unsigned short*)(ws + 36765696);   // 2,359,296 u16

    prep1<<<1376, 256, 0, stream>>>(w, dlat, mw, mb, wsq, wb, s);
    prep2<<<64 + NB_ * 32 * 6, 256, 0, stream>>>(x, s, wsq, dmod, xt);
    conv_mfma<<<512, 256, 0, stream>>>(xt, wb, dmod, out);
}